// Round 3
// baseline (213.904 us; speedup 1.0000x reference)
//
#include <hip/hip_runtime.h>
#include <stdint.h>

#define N_NODES 100000
#define N_EDGES 600000
#define FEAT 128
#define NTILES ((N_NODES + 63) / 64)     // 1563
#define GEMM_BLOCKS 512
#define EDGE_BLOCKS 2048

typedef __attribute__((ext_vector_type(8))) short short8;
typedef __attribute__((ext_vector_type(4))) float floatx4;

__device__ __forceinline__ unsigned f2bf_u(float f) {
    unsigned u = __builtin_bit_cast(unsigned, f);
    return (u + 0x7FFFu + ((u >> 16) & 1u)) >> 16;   // RNE, returns 16-bit value
}
__device__ __forceinline__ short f2bf(float f) { return (short)f2bf_u(f); }
__device__ __forceinline__ float bflo(int w) {
    return __builtin_bit_cast(float, (unsigned)w << 16);
}
__device__ __forceinline__ float bfhi(int w) {
    return __builtin_bit_cast(float, (unsigned)w & 0xFFFF0000u);
}

// Y[m] layout (permuted, 256 bf16 per row):
//   u-part positions p in [0,128):  y[m*256 + p]       = (x[m] @ W1_top)[(p&7)*16 + (p>>3)]
//   v-part positions p in [0,128):  y[m*256 + 128 + p] = (x[m] @ W1_bot)[(p&7)*16 + (p>>3)]
// pw[p] = { b1[j], W2[j] } with j = (p&7)*16 + (p>>3)

__global__ __launch_bounds__(256, 2) void node_gemm_kernel(
    const float* __restrict__ x, const float* __restrict__ w1,
    const float* __restrict__ b1, const float* __restrict__ w2,
    short* __restrict__ y, float2* __restrict__ pw)
{
    __shared__ short lds_b[16 * 256 * 8];   // 64 KB, chunk-major [c=k/8][n][j=k%8]

    const int tid = threadIdx.x;

    if (blockIdx.x == 0 && tid < 128) {
        int j = (tid & 7) * 16 + (tid >> 3);
        pw[tid] = make_float2(b1[j], w2[j]);
    }

    // Stage W1 fp32 -> bf16 LDS (once per block). i = k*256 + n, coalesced in n.
    for (int i = tid; i < 32768; i += 256) {
        int k = i >> 8, n = i & 255;
        float f = (n < FEAT) ? w1[k * FEAT + n] : w1[(FEAT + k) * FEAT + (n - FEAT)];
        lds_b[(((k >> 3) << 8) + n) * 8 + (k & 7)] = f2bf(f);
    }
    __syncthreads();

    const int lane = tid & 63;
    const int wave = tid >> 6;
    const int nl = lane & 15;
    const int q  = lane >> 4;

    int t = blockIdx.x;
    float4 cur[8];
    if (t < NTILES) {
        int node = t * 64 + wave * 16 + nl;
        int nsrc = node < N_NODES ? node : N_NODES - 1;
        const float* bp = x + (size_t)nsrc * FEAT + q * 8;
#pragma unroll
        for (int s = 0; s < 4; ++s) {
            cur[2 * s]     = *(const float4*)(bp + s * 32);
            cur[2 * s + 1] = *(const float4*)(bp + s * 32 + 4);
        }
    }

    for (; t < NTILES; ) {
        int tn = t + GEMM_BLOCKS;
        float4 nxt[8];
        if (tn < NTILES) {
            int node = tn * 64 + wave * 16 + nl;
            int nsrc = node < N_NODES ? node : N_NODES - 1;
            const float* bp = x + (size_t)nsrc * FEAT + q * 8;
#pragma unroll
            for (int s = 0; s < 4; ++s) {
                nxt[2 * s]     = *(const float4*)(bp + s * 32);
                nxt[2 * s + 1] = *(const float4*)(bp + s * 32 + 4);
            }
        }

        // convert cur -> A fragments: lane holds A[m=nl][k=32s+8q+j]
        short8 a[4];
#pragma unroll
        for (int s = 0; s < 4; ++s) {
            const float* f0 = (const float*)&cur[2 * s];
            const float* f1 = (const float*)&cur[2 * s + 1];
            short8 av;
            av[0] = f2bf(f0[0]); av[1] = f2bf(f0[1]); av[2] = f2bf(f0[2]); av[3] = f2bf(f0[3]);
            av[4] = f2bf(f1[0]); av[5] = f2bf(f1[1]); av[6] = f2bf(f1[2]); av[7] = f2bf(f1[3]);
            a[s] = av;
        }

        floatx4 acc[16];
#pragma unroll
        for (int nt = 0; nt < 16; ++nt) acc[nt] = (floatx4)(0.0f);

#pragma unroll
        for (int s = 0; s < 4; ++s) {
            const int crow = (s * 4 + q) << 8;
#pragma unroll
            for (int nt = 0; nt < 16; ++nt) {
                short8 bf = *(const short8*)(lds_b + ((crow + nt * 16 + nl) << 3));
                acc[nt] = __builtin_amdgcn_mfma_f32_16x16x32_bf16(a[s], bf, acc[nt], 0, 0, 0);
            }
        }

        // epilogue: lane nl packs its 8 u-values / 8 v-values contiguously (16 B each)
        const int m0 = t * 64 + wave * 16;
#pragma unroll
        for (int r = 0; r < 4; ++r) {
            int m = m0 + q * 4 + r;
            if (m < N_NODES) {
                int up[4], vp[4];
#pragma unroll
                for (int d = 0; d < 4; ++d) {
                    up[d] = (int)(f2bf_u(acc[2 * d][r])     | (f2bf_u(acc[2 * d + 1][r]) << 16));
                    vp[d] = (int)(f2bf_u(acc[8 + 2 * d][r]) | (f2bf_u(acc[9 + 2 * d][r]) << 16));
                }
                short* yr = y + (size_t)m * 256 + nl * 8;
                *(int4*)yr         = make_int4(up[0], up[1], up[2], up[3]);
                *(int4*)(yr + 128) = make_int4(vp[0], vp[1], vp[2], vp[3]);
            }
        }

#pragma unroll
        for (int s = 0; s < 8; ++s) cur[s] = nxt[s];
        t = tn;
    }
}

__device__ __forceinline__ float dotacc(int4 u, int4 v, const float2* pwr, int base, float p) {
    int uu[4] = {u.x, u.y, u.z, u.w};
    int vv[4] = {v.x, v.y, v.z, v.w};
#pragma unroll
    for (int d = 0; d < 4; ++d) {
        float h0 = bflo(uu[d]) + bflo(vv[d]) + pwr[base + 2 * d].x;
        float h1 = bfhi(uu[d]) + bfhi(vv[d]) + pwr[base + 2 * d + 1].x;
        p = fmaf(fmaxf(h0, 0.0f), pwr[base + 2 * d].y, p);
        p = fmaf(fmaxf(h1, 0.0f), pwr[base + 2 * d + 1].y, p);
    }
    return p;
}

// 8 lanes per edge, 16 features (32 B) per lane, unroll-2 for MLP.
__global__ __launch_bounds__(256) void edge_kernel(
    const short* __restrict__ y, const int* __restrict__ eidx,
    const float2* __restrict__ pw, const float* __restrict__ b2,
    float* __restrict__ out)
{
    const int gt = blockIdx.x * 256 + threadIdx.x;
    const int l = gt & 7;
    const int g = gt >> 3;
    const int G = (EDGE_BLOCKS * 256) / 8;   // 65536 groups

    float2 pwr[16];
#pragma unroll
    for (int i = 0; i < 16; ++i) pwr[i] = pw[l * 16 + i];
    const float bias2 = b2[0];

    for (int e = g; e < N_EDGES; e += 2 * G) {
        int e2 = e + G;
        bool h2 = e2 < N_EDGES;
        int r1 = eidx[e];
        int c1 = eidx[N_EDGES + e];
        int r2 = h2 ? eidx[e2] : 0;
        int c2 = h2 ? eidx[N_EDGES + e2] : 0;

        const short* u1p = y + (size_t)r1 * 256 + l * 16;
        const short* v1p = y + (size_t)c1 * 256 + 128 + l * 16;
        const short* u2p = y + (size_t)r2 * 256 + l * 16;
        const short* v2p = y + (size_t)c2 * 256 + 128 + l * 16;
        int4 ua1 = *(const int4*)u1p, ub1 = *(const int4*)(u1p + 8);
        int4 va1 = *(const int4*)v1p, vb1 = *(const int4*)(v1p + 8);
        int4 ua2 = *(const int4*)u2p, ub2 = *(const int4*)(u2p + 8);
        int4 va2 = *(const int4*)v2p, vb2 = *(const int4*)(v2p + 8);

        float p1 = 0.0f, p2 = 0.0f;
        p1 = dotacc(ua1, va1, pwr, 0, p1);
        p1 = dotacc(ub1, vb1, pwr, 8, p1);
        p2 = dotacc(ua2, va2, pwr, 0, p2);
        p2 = dotacc(ub2, vb2, pwr, 8, p2);

        p1 += __shfl_xor(p1, 1);  p2 += __shfl_xor(p2, 1);
        p1 += __shfl_xor(p1, 2);  p2 += __shfl_xor(p2, 2);
        p1 += __shfl_xor(p1, 4);  p2 += __shfl_xor(p2, 4);

        if (l == 0) {
            out[e] = 1.0f / (1.0f + __expf(-(p1 + bias2)));
            if (h2) out[e2] = 1.0f / (1.0f + __expf(-(p2 + bias2)));
        }
    }
}

extern "C" void kernel_launch(void* const* d_in, const int* in_sizes, int n_in,
                              void* d_out, int out_size, void* d_ws, size_t ws_size,
                              hipStream_t stream) {
    const float* x  = (const float*)d_in[0];
    const int*   ei = (const int*)d_in[1];
    const float* W1 = (const float*)d_in[2];
    const float* b1 = (const float*)d_in[3];
    const float* W2 = (const float*)d_in[4];
    const float* b2 = (const float*)d_in[5];
    float* out = (float*)d_out;

    short*  ybf = (short*)d_ws;                              // 100000*256 shorts = 51.2 MB
    float2* pw  = (float2*)(ybf + (size_t)N_NODES * 256);    // 128 float2 = 1 KB

    node_gemm_kernel<<<GEMM_BLOCKS, 256, 0, stream>>>(x, W1, b1, W2, ybf, pw);
    edge_kernel<<<EDGE_BLOCKS, 256, 0, stream>>>(ybf, ei, pw, b2, out);
}